// Round 4
// baseline (280.008 us; speedup 1.0000x reference)
//
#include <hip/hip_runtime.h>

#define BATCH 65536

typedef __attribute__((ext_vector_type(8))) short bf16x8;
typedef __attribute__((ext_vector_type(4))) float f32x4;

__device__ __forceinline__ unsigned short f2bf(float f) {
  unsigned int u = __float_as_uint(f);
  u += 0x7fffu + ((u >> 16) & 1u);   // RNE
  return (unsigned short)(u >> 16);
}
__device__ __forceinline__ float bf2f(unsigned short h) {
  return __uint_as_float(((unsigned)h) << 16);
}

// tanh(o) * sigmoid(u), overflow-proof: clamps are no-ops for legit data
// (|u|,|o| < ~10 here) but prevent exp-overflow -> -inf/inf = NaN if any
// intermediate is ever garbage-large.
__device__ __forceinline__ float gru_act(float u, float o) {
  u = fminf(fmaxf(u, -60.0f), 60.0f);
  o = fminf(fmaxf(o, -30.0f), 30.0f);
  float a  = __expf(-u);
  float a2 = __expf(-2.0f * o);
  return (1.0f - a2) / ((1.0f + a) * (1.0f + a2));
}

// conv 3x3 SAME on 3x3 grid, unrolled tap value
__device__ __forceinline__ float conv_tap(const float* __restrict__ w, int co, int ci,
                                          int p, int q, int CINTOT) {
  int pi = p / 3, pj = p % 3, qi = q / 3, qj = q % 3;
  int di = qi - pi + 1, dj = qj - pj + 1;
  if ((unsigned)di < 3u && (unsigned)dj < 3u)
    return w[((co * CINTOT + ci) * 3 + di) * 3 + dj];
  return 0.0f;
}

// BT[g][n][k] bf16, n = co*9+p, k = ci*9+q
__global__ void build_bt(const float* __restrict__ wu, const float* __restrict__ wo,
                         unsigned short* __restrict__ BT, int COUT, int CINX, int CINTOT) {
  int NG = COUT * 9, K = CINX * 9;
  int total = 2 * NG * K;
  int e = blockIdx.x * 256 + threadIdx.x;
  if (e >= total) return;
  int g = e / (NG * K);
  int rem = e - g * (NG * K);
  int n = rem / K, k = rem - n * K;
  BT[e] = f2bf(conv_tap(g ? wo : wu, n / 9, k / 9, n % 9, k % 9, CINTOT));
}

// A1 transposed: [g][q][c], c = col n in [0,288), q = input tap in [0,9)
__global__ void build_a1(const float* __restrict__ wu, const float* __restrict__ wo,
                         float* __restrict__ A1) {
  int e = blockIdx.x * 256 + threadIdx.x;
  if (e >= 5184) return;
  int g = e / 2592;
  int rem = e - g * 2592;
  int q = rem / 288, c = rem - q * 288;
  A1[e] = conv_tap(g ? wo : wu, c / 9, 0, c % 9, q, 33);
}

// ---------------- LDS layout (bytes), lifetimes barrier-separated ----------------
// [0,     40960) x1l (L1 write .. L2 last af read)
//                -> x3l [0,18688) (L3 epilogue .. dense)   [disjoint from wl]
// [20480, 25664) wl  (post-L2 .. dense)
// [25664, 25700) blb
// [40960, 65536) Bl: L2 uses 384x64=24576; L3 uses 288x64=18432
// [65536, 68608) xl (L1 only)
// [65536, 69632) Al (L3 A-tile, 64x64)
#define OFF_X1L 0
#define OFF_X3L 0
#define OFF_WL 20480
#define OFF_BLB 25664
#define OFF_BL 40960
#define OFF_XL 65536
#define OFF_AL 65536
#define SMEM_BYTES 69632

__global__ __launch_bounds__(256, 2) void megafused(
    const float* __restrict__ xin, const float* __restrict__ A1,
    const float* __restrict__ b1u, const float* __restrict__ b1o,
    const unsigned short* __restrict__ BT2,
    const float* __restrict__ b2u, const float* __restrict__ b2o,
    const unsigned short* __restrict__ BT3,
    const float* __restrict__ b3u, const float* __restrict__ b3o,
    const float* __restrict__ wd, const float* __restrict__ bd,
    float* __restrict__ x1, float* __restrict__ x2,
    float* __restrict__ x3, float* __restrict__ out) {
  __shared__ __align__(16) char smem[SMEM_BYTES];
  char* x1l = smem + OFF_X1L;
  char* Bl = smem + OFF_BL;
  char* Al = smem + OFF_AL;
  unsigned short* x3l = (unsigned short*)(smem + OFF_X3L);
  float* xl = (float*)(smem + OFF_XL);
  float* wl = (float*)(smem + OFF_WL);
  float* blb = (float*)(smem + OFF_BLB);

  const int tid = threadIdx.x;
  const int lane = tid & 63;
  const int wid = tid >> 6;
  const int lrow = lane & 15;
  const int jc = lane >> 4;
  const int r0 = blockIdx.x * 64;

  // stage x input
  for (int c = tid; c < 576; c += 256) xl[(c / 9) * 12 + (c % 9)] = xin[(size_t)r0 * 9 + c];
  __syncthreads();

  // ---- L1: exact fp32, lanes = cols (verbatim round 2) ----
  {
    float au0[9], ao0[9], au1[9], ao1[9];
    const int c1 = tid, c2 = tid + 256;
    const bool has2 = (c2 < 288);
#pragma unroll
    for (int q = 0; q < 9; ++q) {
      au0[q] = A1[q * 288 + c1];
      ao0[q] = A1[2592 + q * 288 + c1];
      au1[q] = has2 ? A1[q * 288 + c2] : 0.0f;
      ao1[q] = has2 ? A1[2592 + q * 288 + c2] : 0.0f;
    }
    float bu0 = b1u[c1 / 9], bo0 = b1o[c1 / 9];
    float bu1 = has2 ? b1u[c2 / 9] : 0.0f;
    float bo1 = has2 ? b1o[c2 / 9] : 0.0f;
    for (int r = 0; r < 64; ++r) {
      float xr[9];
#pragma unroll
      for (int q = 0; q < 9; ++q) xr[q] = xl[r * 12 + q];
      float u0 = bu0, o0 = bo0, u1 = bu1, o1 = bo1;
#pragma unroll
      for (int q = 0; q < 9; ++q) {
        u0 = fmaf(au0[q], xr[q], u0);
        o0 = fmaf(ao0[q], xr[q], o0);
        u1 = fmaf(au1[q], xr[q], u1);
        o1 = fmaf(ao1[q], xr[q], o1);
      }
      float v0 = gru_act(u0, o0);
      x1[(size_t)(r0 + r) * 288 + c1] = v0;
      *(unsigned short*)(x1l + r * 640 + (((c1 >> 3) ^ (r & 7)) << 4) + (c1 & 7) * 2) = f2bf(v0);
      if (has2) {
        float v1 = gru_act(u1, o1);
        x1[(size_t)(r0 + r) * 288 + c2] = v1;
        *(unsigned short*)(x1l + r * 640 + (((c2 >> 3) ^ (r & 7)) << 4) + (c2 & 7) * 2) = f2bf(v1);
      }
    }
  }

  // ---- L2: x1l(bf16) x BT2 -> x2 global fp32 (verbatim round 2) ----
  for (int nch = 0; nch < 3; ++nch) {
    const int n0 = nch * 192;
    f32x4 acc[4][2][3] = {};
    for (int kt = 0; kt < 9; ++kt) {
#pragma unroll
      for (int ci = 0; ci < 6; ++ci) {
        int c = ci * 256 + tid;              // 1536 chunks = 384 rows x 4
        int row = c >> 2, part = c & 3;
        int ng = (row >= 192) ? (576 + n0 + row - 192) : (n0 + row);
        bf16x8 v = *(const bf16x8*)(BT2 + (size_t)ng * 288 + kt * 32 + part * 8);
        *(bf16x8*)(Bl + row * 64 + ((part ^ ((row >> 1) & 3)) << 4)) = v;
      }
      __syncthreads();   // Bl ready; (first iter) x1l writes visible
      bf16x8 af[4];
#pragma unroll
      for (int m = 0; m < 4; ++m) {
        int row = m * 16 + lrow;
        int c8 = kt * 4 + jc;
        af[m] = *(const bf16x8*)(x1l + row * 640 + ((c8 ^ (row & 7)) << 4));
      }
      bf16x8 bfr[2][3];
#pragma unroll
      for (int g = 0; g < 2; ++g)
#pragma unroll
        for (int f = 0; f < 3; ++f) {
          int rb = g * 192 + (wid * 3 + f) * 16 + lrow;
          bfr[g][f] = *(const bf16x8*)(Bl + rb * 64 + ((jc ^ ((rb >> 1) & 3)) << 4));
        }
#pragma unroll
      for (int m = 0; m < 4; ++m)
#pragma unroll
        for (int g = 0; g < 2; ++g)
#pragma unroll
          for (int f = 0; f < 3; ++f)
            acc[m][g][f] = __builtin_amdgcn_mfma_f32_16x16x32_bf16(
                af[m], bfr[g][f], acc[m][g][f], 0, 0, 0);
      __syncthreads();   // Bl consumers done before next stage
    }
    // epilogue: C/D col = lane&15, row = (lane>>4)*4 + t
#pragma unroll
    for (int m = 0; m < 4; ++m)
#pragma unroll
      for (int f = 0; f < 3; ++f) {
        int n = n0 + (wid * 3 + f) * 16 + lrow;
        float bU = b2u[n / 9], bO = b2o[n / 9];
        f32x4 u = acc[m][0][f], o = acc[m][1][f];
#pragma unroll
        for (int t = 0; t < 4; ++t) {
          int r = r0 + m * 16 + jc * 4 + t;
          x2[(size_t)r * 576 + n] = gru_act(u[t] + bU, o[t] + bO);
        }
      }
  }
  __syncthreads();   // x1l / Bl(L2) dead beyond this point

  // stage dense weights (disjoint region from x3l)
  for (int c = tid; c < 1296; c += 256) wl[c] = wd[c];
  if (tid < 9) blb[tid] = bd[tid];

  // ---- L3: x2 (global fp32, L2/LLC-hot: same rows this block wrote) x BT3 ----
  {
    f32x4 acc[4][2][3] = {};
    for (int kt = 0; kt < 18; ++kt) {
      // stage A: 256 chunks = 64 rows x 4 parts, fp32 -> bf16
      {
        int c = tid;
        int row = c >> 2, part = c & 3;
        const float* gp = x2 + (size_t)(r0 + row) * 576 + kt * 32 + part * 8;
        float4 q0 = *(const float4*)gp;
        float4 q1 = *(const float4*)(gp + 4);
        bf16x8 h;
        h[0] = (short)f2bf(q0.x); h[1] = (short)f2bf(q0.y);
        h[2] = (short)f2bf(q0.z); h[3] = (short)f2bf(q0.w);
        h[4] = (short)f2bf(q1.x); h[5] = (short)f2bf(q1.y);
        h[6] = (short)f2bf(q1.z); h[7] = (short)f2bf(q1.w);
        *(bf16x8*)(Al + row * 64 + ((part ^ ((row >> 1) & 3)) << 4)) = h;
      }
      // stage B: 1152 chunks = 288 rows x 4 parts
      for (int c = tid; c < 1152; c += 256) {
        int row = c >> 2, part = c & 3;
        bf16x8 v = *(const bf16x8*)(BT3 + (size_t)row * 576 + kt * 32 + part * 8);
        *(bf16x8*)(Bl + row * 64 + ((part ^ ((row >> 1) & 3)) << 4)) = v;
      }
      __syncthreads();
      if (wid < 3) {
        bf16x8 af[4];
#pragma unroll
        for (int m = 0; m < 4; ++m) {
          int row = m * 16 + lrow;
          af[m] = *(const bf16x8*)(Al + row * 64 + ((jc ^ ((row >> 1) & 3)) << 4));
        }
        bf16x8 bfr[2][3];
#pragma unroll
        for (int g = 0; g < 2; ++g)
#pragma unroll
          for (int f = 0; f < 3; ++f) {
            int rb = g * 144 + (wid * 3 + f) * 16 + lrow;
            bfr[g][f] = *(const bf16x8*)(Bl + rb * 64 + ((jc ^ ((rb >> 1) & 3)) << 4));
          }
#pragma unroll
        for (int m = 0; m < 4; ++m)
#pragma unroll
          for (int g = 0; g < 2; ++g)
#pragma unroll
            for (int f = 0; f < 3; ++f)
              acc[m][g][f] = __builtin_amdgcn_mfma_f32_16x16x32_bf16(
                  af[m], bfr[g][f], acc[m][g][f], 0, 0, 0);
      }
      __syncthreads();
    }
    // epilogue: act -> x3 global fp32 + x3l (LDS bf16)
    if (wid < 3) {
#pragma unroll
      for (int m = 0; m < 4; ++m)
#pragma unroll
        for (int f = 0; f < 3; ++f) {
          int n = (wid * 3 + f) * 16 + lrow;
          float bU = b3u[n / 9], bO = b3o[n / 9];
          f32x4 u = acc[m][0][f], o = acc[m][1][f];
#pragma unroll
          for (int t = 0; t < 4; ++t) {
            int r = m * 16 + jc * 4 + t;
            float v = gru_act(u[t] + bU, o[t] + bO);
            x3[(size_t)(r0 + r) * 144 + n] = v;
            x3l[r * 146 + n] = f2bf(v);
          }
        }
    }
  }
  __syncthreads();   // x3l ready

  // ---- dense head (verbatim round 2): 3 waves, 3 cols each ----
  if (wid < 3) {
    int drow = lane;
    int jb = wid * 3;
    float s0 = blb[jb], s1 = blb[jb + 1], s2 = blb[jb + 2];
    for (int k = 0; k < 144; k += 2) {
      unsigned pr = *(const unsigned*)&x3l[drow * 146 + k];
      float v0 = bf2f((unsigned short)pr);
      float v1 = bf2f((unsigned short)(pr >> 16));
      s0 = fmaf(v0, wl[jb * 144 + k], s0);
      s0 = fmaf(v1, wl[jb * 144 + k + 1], s0);
      s1 = fmaf(v0, wl[(jb + 1) * 144 + k], s1);
      s1 = fmaf(v1, wl[(jb + 1) * 144 + k + 1], s1);
      s2 = fmaf(v0, wl[(jb + 2) * 144 + k], s2);
      s2 = fmaf(v1, wl[(jb + 2) * 144 + k + 1], s2);
    }
    size_t ob = (size_t)(r0 + drow) * 9 + jb;
    out[ob] = s0; out[ob + 1] = s1; out[ob + 2] = s2;
  }
}

extern "C" void kernel_launch(void* const* d_in, const int* in_sizes, int n_in,
                              void* d_out, int out_size, void* d_ws, size_t ws_size,
                              hipStream_t stream) {
  const float* inputs = (const float*)d_in[0];
  const float* wd  = (const float*)d_in[1];
  const float* bd  = (const float*)d_in[2];
  const float* w1u = (const float*)d_in[3];
  const float* b1u = (const float*)d_in[4];
  const float* w1o = (const float*)d_in[7];
  const float* b1o = (const float*)d_in[8];
  const float* w2u = (const float*)d_in[9];
  const float* b2u = (const float*)d_in[10];
  const float* w2o = (const float*)d_in[13];
  const float* b2o = (const float*)d_in[14];
  const float* w3u = (const float*)d_in[15];
  const float* b3u = (const float*)d_in[16];
  const float* w3o = (const float*)d_in[19];
  const float* b3o = (const float*)d_in[20];

  float* out = (float*)d_out;                    // [B][9]
  float* x1 = out + (size_t)BATCH * 9;           // [B][288]
  float* x2 = x1 + (size_t)BATCH * 288;          // [B][576]
  float* x3 = x2 + (size_t)BATCH * 576;          // [B][144]

  unsigned short* BT2 = (unsigned short*)d_ws;   // [2][576][288] bf16
  unsigned short* BT3 = BT2 + 331776;            // [2][144][576] bf16
  float* A1 = (float*)((char*)d_ws + 995328);    // [2][9][288] fp32

  build_bt<<<1296, 256, 0, stream>>>(w2u, w2o, BT2, 64, 32, 96);
  build_bt<<<648, 256, 0, stream>>>(w3u, w3o, BT3, 16, 64, 80);
  build_a1<<<21, 256, 0, stream>>>(w1u, w1o, A1);

  megafused<<<BATCH / 64, 256, 0, stream>>>(inputs, A1, b1u, b1o, BT2, b2u, b2o,
                                            BT3, b3u, b3o, wd, bd, x1, x2, x3, out);
}

// Round 5
// 185.736 us; speedup vs baseline: 1.5076x; 1.5076x over previous
//
#include <hip/hip_runtime.h>

#define BATCH 65536

typedef __attribute__((ext_vector_type(8))) short bf16x8;
typedef __attribute__((ext_vector_type(4))) float f32x4;

__device__ __forceinline__ unsigned short f2bf(float f) {
  unsigned int u = __float_as_uint(f);
  u += 0x7fffu + ((u >> 16) & 1u);   // RNE
  return (unsigned short)(u >> 16);
}
__device__ __forceinline__ float bf2f(unsigned short h) {
  return __uint_as_float(((unsigned)h) << 16);
}

// tanh(o) * sigmoid(u), overflow-proof (clamps are no-ops for legit data)
__device__ __forceinline__ float gru_act(float u, float o) {
  u = fminf(fmaxf(u, -60.0f), 60.0f);
  o = fminf(fmaxf(o, -30.0f), 30.0f);
  float a  = __expf(-u);
  float a2 = __expf(-2.0f * o);
  return (1.0f - a2) / ((1.0f + a) * (1.0f + a2));
}

// conv 3x3 SAME on 3x3 grid, unrolled tap value
__device__ __forceinline__ float conv_tap(const float* __restrict__ w, int co, int ci,
                                          int p, int q, int CINTOT) {
  int pi = p / 3, pj = p % 3, qi = q / 3, qj = q % 3;
  int di = qi - pi + 1, dj = qj - pj + 1;
  if ((unsigned)di < 3u && (unsigned)dj < 3u)
    return w[((co * CINTOT + ci) * 3 + di) * 3 + dj];
  return 0.0f;
}

// BT[g][n][k] bf16, n = co*9+p, k = ci*9+q
__global__ void build_bt(const float* __restrict__ wu, const float* __restrict__ wo,
                         unsigned short* __restrict__ BT, int COUT, int CINX, int CINTOT) {
  int NG = COUT * 9, K = CINX * 9;
  int total = 2 * NG * K;
  int e = blockIdx.x * 256 + threadIdx.x;
  if (e >= total) return;
  int g = e / (NG * K);
  int rem = e - g * (NG * K);
  int n = rem / K, k = rem - n * K;
  BT[e] = f2bf(conv_tap(g ? wo : wu, n / 9, k / 9, n % 9, k % 9, CINTOT));
}

// A1 transposed: [g][q][c], c = col n in [0,288), q = input tap in [0,9)
__global__ void build_a1(const float* __restrict__ wu, const float* __restrict__ wo,
                         float* __restrict__ A1) {
  int e = blockIdx.x * 256 + threadIdx.x;
  if (e >= 5184) return;
  int g = e / 2592;
  int rem = e - g * 2592;
  int q = rem / 288, c = rem - q * 288;
  A1[e] = conv_tap(g ? wo : wu, c / 9, 0, c % 9, q, 33);
}

// ---------------- LDS layout (bytes), lifetimes barrier-separated ----------------
#define OFF_X1L 0
#define OFF_X3L 0
#define OFF_WL 20480
#define OFF_BLB 25664
#define OFF_BL 40960
#define OFF_XL 65536
#define OFF_AL 65536
#define SMEM_BYTES 69632

__global__ __launch_bounds__(256, 2) void megafused(
    const float* __restrict__ xin, const float* __restrict__ A1,
    const float* __restrict__ b1u, const float* __restrict__ b1o,
    const unsigned short* __restrict__ BT2,
    const float* __restrict__ b2u, const float* __restrict__ b2o,
    const unsigned short* __restrict__ BT3,
    const float* __restrict__ b3u, const float* __restrict__ b3o,
    const float* __restrict__ wd, const float* __restrict__ bd,
    float* __restrict__ x1, float* __restrict__ x2,
    float* __restrict__ x3, float* __restrict__ out) {
  __shared__ __align__(16) char smem[SMEM_BYTES];
  char* x1l = smem + OFF_X1L;
  char* Bl = smem + OFF_BL;
  char* Al = smem + OFF_AL;
  unsigned short* x3l = (unsigned short*)(smem + OFF_X3L);
  float* xl = (float*)(smem + OFF_XL);
  float* wl = (float*)(smem + OFF_WL);
  float* blb = (float*)(smem + OFF_BLB);

  const int tid = threadIdx.x;
  const int lane = tid & 63;
  const int wid = tid >> 6;
  const int lrow = lane & 15;
  const int jc = lane >> 4;
  const int r0 = blockIdx.x * 64;

  // stage x input
  for (int c = tid; c < 576; c += 256) xl[(c / 9) * 12 + (c % 9)] = xin[(size_t)r0 * 9 + c];
  __syncthreads();

  // ---- L1: exact fp32, lanes = cols (verbatim round 4) ----
  {
    float au0[9], ao0[9], au1[9], ao1[9];
    const int c1 = tid, c2 = tid + 256;
    const bool has2 = (c2 < 288);
#pragma unroll
    for (int q = 0; q < 9; ++q) {
      au0[q] = A1[q * 288 + c1];
      ao0[q] = A1[2592 + q * 288 + c1];
      au1[q] = has2 ? A1[q * 288 + c2] : 0.0f;
      ao1[q] = has2 ? A1[2592 + q * 288 + c2] : 0.0f;
    }
    float bu0 = b1u[c1 / 9], bo0 = b1o[c1 / 9];
    float bu1 = has2 ? b1u[c2 / 9] : 0.0f;
    float bo1 = has2 ? b1o[c2 / 9] : 0.0f;
    for (int r = 0; r < 64; ++r) {
      float xr[9];
#pragma unroll
      for (int q = 0; q < 9; ++q) xr[q] = xl[r * 12 + q];
      float u0 = bu0, o0 = bo0, u1 = bu1, o1 = bo1;
#pragma unroll
      for (int q = 0; q < 9; ++q) {
        u0 = fmaf(au0[q], xr[q], u0);
        o0 = fmaf(ao0[q], xr[q], o0);
        u1 = fmaf(au1[q], xr[q], u1);
        o1 = fmaf(ao1[q], xr[q], o1);
      }
      float v0 = gru_act(u0, o0);
      x1[(size_t)(r0 + r) * 288 + c1] = v0;
      *(unsigned short*)(x1l + r * 640 + (((c1 >> 3) ^ (r & 7)) << 4) + (c1 & 7) * 2) = f2bf(v0);
      if (has2) {
        float v1 = gru_act(u1, o1);
        x1[(size_t)(r0 + r) * 288 + c2] = v1;
        *(unsigned short*)(x1l + r * 640 + (((c2 >> 3) ^ (r & 7)) << 4) + (c2 & 7) * 2) = f2bf(v1);
      }
    }
  }

  // ---- L2: x1l(bf16) x BT2 -> x2 global fp32. Flat 27 steps, depth-1 B prefetch ----
  {
    const int srow = tid >> 2, spart = tid & 3;   // staging coords: chunk c = ci*256+tid
    bf16x8 pf[6];
    // loads for step 0 (nch=0, kt=0)
#pragma unroll
    for (int ci = 0; ci < 6; ++ci) {
      int row = (ci * 256 + tid) >> 2;
      int ng = (row >= 192) ? (576 + row - 192) : row;
      pf[ci] = *(const bf16x8*)(BT2 + (size_t)ng * 288 + spart * 8);
    }
    f32x4 acc[4][2][3] = {};
    for (int s = 0; s < 27; ++s) {
      const int kt = s - (s / 9) * 9;
      // write staged B to LDS (waits on pf loads)
#pragma unroll
      for (int ci = 0; ci < 6; ++ci) {
        int row = (ci * 256 + tid) >> 2;
        *(bf16x8*)(Bl + row * 64 + ((spart ^ ((row >> 1) & 3)) << 4)) = pf[ci];
      }
      // issue loads for step s+1 (in flight across barrier + MFMA)
      if (s < 26) {
        int ns = s + 1, nnch = ns / 9, nkt = ns - nnch * 9;
#pragma unroll
        for (int ci = 0; ci < 6; ++ci) {
          int row = (ci * 256 + tid) >> 2;
          int ng = (row >= 192) ? (576 + nnch * 192 + row - 192) : (nnch * 192 + row);
          pf[ci] = *(const bf16x8*)(BT2 + (size_t)ng * 288 + nkt * 32 + spart * 8);
        }
      }
      __syncthreads();   // Bl ready; (first iter) x1l writes visible
      bf16x8 af[4];
#pragma unroll
      for (int m = 0; m < 4; ++m) {
        int row = m * 16 + lrow;
        int c8 = kt * 4 + jc;
        af[m] = *(const bf16x8*)(x1l + row * 640 + ((c8 ^ (row & 7)) << 4));
      }
      bf16x8 bfr[2][3];
#pragma unroll
      for (int g = 0; g < 2; ++g)
#pragma unroll
        for (int f = 0; f < 3; ++f) {
          int rb = g * 192 + (wid * 3 + f) * 16 + lrow;
          bfr[g][f] = *(const bf16x8*)(Bl + rb * 64 + ((jc ^ ((rb >> 1) & 3)) << 4));
        }
#pragma unroll
      for (int m = 0; m < 4; ++m)
#pragma unroll
        for (int g = 0; g < 2; ++g)
#pragma unroll
          for (int f = 0; f < 3; ++f)
            acc[m][g][f] = __builtin_amdgcn_mfma_f32_16x16x32_bf16(
                af[m], bfr[g][f], acc[m][g][f], 0, 0, 0);
      if (kt == 8) {
        // epilogue for nch = s/9 (no LDS touched)
        const int n0 = (s / 9) * 192;
#pragma unroll
        for (int m = 0; m < 4; ++m)
#pragma unroll
          for (int f = 0; f < 3; ++f) {
            int n = n0 + (wid * 3 + f) * 16 + lrow;
            float bU = b2u[n / 9], bO = b2o[n / 9];
            f32x4 u = acc[m][0][f], o = acc[m][1][f];
#pragma unroll
            for (int t = 0; t < 4; ++t) {
              int r = r0 + m * 16 + jc * 4 + t;
              x2[(size_t)r * 576 + n] = gru_act(u[t] + bU, o[t] + bO);
            }
            acc[m][0][f] = (f32x4){0.f, 0.f, 0.f, 0.f};
            acc[m][1][f] = (f32x4){0.f, 0.f, 0.f, 0.f};
          }
      }
      __syncthreads();   // Bl consumers done before next stage
    }
  }
  __syncthreads();   // x1l / Bl(L2) dead; x2 stores drained (vmcnt 0 at barrier)

  // stage dense weights (disjoint region from x3l)
  for (int c = tid; c < 1296; c += 256) wl[c] = wd[c];
  if (tid < 9) blb[tid] = bd[tid];

  // ---- L3: x2 (L2-hot readback) x BT3, depth-1 prefetch of A and B ----
  {
    const int srow = tid >> 2, spart = tid & 3;
    float4 pa0, pa1;
    bf16x8 pb[5];
    // loads for kt=0
    {
      const float* gp = x2 + (size_t)(r0 + srow) * 576 + spart * 8;
      pa0 = *(const float4*)gp;
      pa1 = *(const float4*)(gp + 4);
    }
#pragma unroll
    for (int j = 0; j < 5; ++j) {
      int c = j * 256 + tid;
      if (c < 1152) {
        int row = c >> 2, part = c & 3;
        pb[j] = *(const bf16x8*)(BT3 + (size_t)row * 576 + part * 8);
      }
    }
    f32x4 acc[4][2][3] = {};
    for (int kt = 0; kt < 18; ++kt) {
      // A: convert + write
      {
        bf16x8 h;
        h[0] = (short)f2bf(pa0.x); h[1] = (short)f2bf(pa0.y);
        h[2] = (short)f2bf(pa0.z); h[3] = (short)f2bf(pa0.w);
        h[4] = (short)f2bf(pa1.x); h[5] = (short)f2bf(pa1.y);
        h[6] = (short)f2bf(pa1.z); h[7] = (short)f2bf(pa1.w);
        *(bf16x8*)(Al + srow * 64 + ((spart ^ ((srow >> 1) & 3)) << 4)) = h;
      }
      // B: write
#pragma unroll
      for (int j = 0; j < 5; ++j) {
        int c = j * 256 + tid;
        if (c < 1152) {
          int row = c >> 2, part = c & 3;
          *(bf16x8*)(Bl + row * 64 + ((part ^ ((row >> 1) & 3)) << 4)) = pb[j];
        }
      }
      // issue loads for kt+1
      if (kt < 17) {
        const float* gp = x2 + (size_t)(r0 + srow) * 576 + (kt + 1) * 32 + spart * 8;
        pa0 = *(const float4*)gp;
        pa1 = *(const float4*)(gp + 4);
#pragma unroll
        for (int j = 0; j < 5; ++j) {
          int c = j * 256 + tid;
          if (c < 1152) {
            int row = c >> 2, part = c & 3;
            pb[j] = *(const bf16x8*)(BT3 + (size_t)row * 576 + (kt + 1) * 32 + part * 8);
          }
        }
      }
      __syncthreads();
      if (wid < 3) {
        bf16x8 af[4];
#pragma unroll
        for (int m = 0; m < 4; ++m) {
          int row = m * 16 + lrow;
          af[m] = *(const bf16x8*)(Al + row * 64 + ((jc ^ ((row >> 1) & 3)) << 4));
        }
        bf16x8 bfr[2][3];
#pragma unroll
        for (int g = 0; g < 2; ++g)
#pragma unroll
          for (int f = 0; f < 3; ++f) {
            int rb = g * 144 + (wid * 3 + f) * 16 + lrow;
            bfr[g][f] = *(const bf16x8*)(Bl + rb * 64 + ((jc ^ ((rb >> 1) & 3)) << 4));
          }
#pragma unroll
        for (int m = 0; m < 4; ++m)
#pragma unroll
          for (int g = 0; g < 2; ++g)
#pragma unroll
            for (int f = 0; f < 3; ++f)
              acc[m][g][f] = __builtin_amdgcn_mfma_f32_16x16x32_bf16(
                  af[m], bfr[g][f], acc[m][g][f], 0, 0, 0);
      }
      __syncthreads();
    }
    // epilogue: act -> x3 global fp32 + x3l (LDS bf16)
    if (wid < 3) {
#pragma unroll
      for (int m = 0; m < 4; ++m)
#pragma unroll
        for (int f = 0; f < 3; ++f) {
          int n = (wid * 3 + f) * 16 + lrow;
          float bU = b3u[n / 9], bO = b3o[n / 9];
          f32x4 u = acc[m][0][f], o = acc[m][1][f];
#pragma unroll
          for (int t = 0; t < 4; ++t) {
            int r = m * 16 + jc * 4 + t;
            float v = gru_act(u[t] + bU, o[t] + bO);
            x3[(size_t)(r0 + r) * 144 + n] = v;
            x3l[r * 146 + n] = f2bf(v);
          }
        }
    }
  }
  __syncthreads();   // x3l ready

  // ---- dense head: 3 waves, 3 cols each ----
  if (wid < 3) {
    int drow = lane;
    int jb = wid * 3;
    float s0 = blb[jb], s1 = blb[jb + 1], s2 = blb[jb + 2];
    for (int k = 0; k < 144; k += 2) {
      unsigned pr = *(const unsigned*)&x3l[drow * 146 + k];
      float v0 = bf2f((unsigned short)pr);
      float v1 = bf2f((unsigned short)(pr >> 16));
      s0 = fmaf(v0, wl[jb * 144 + k], s0);
      s0 = fmaf(v1, wl[jb * 144 + k + 1], s0);
      s1 = fmaf(v0, wl[(jb + 1) * 144 + k], s1);
      s1 = fmaf(v1, wl[(jb + 1) * 144 + k + 1], s1);
      s2 = fmaf(v0, wl[(jb + 2) * 144 + k], s2);
      s2 = fmaf(v1, wl[(jb + 2) * 144 + k + 1], s2);
    }
    size_t ob = (size_t)(r0 + drow) * 9 + jb;
    out[ob] = s0; out[ob + 1] = s1; out[ob + 2] = s2;
  }
}

extern "C" void kernel_launch(void* const* d_in, const int* in_sizes, int n_in,
                              void* d_out, int out_size, void* d_ws, size_t ws_size,
                              hipStream_t stream) {
  const float* inputs = (const float*)d_in[0];
  const float* wd  = (const float*)d_in[1];
  const float* bd  = (const float*)d_in[2];
  const float* w1u = (const float*)d_in[3];
  const float* b1u = (const float*)d_in[4];
  const float* w1o = (const float*)d_in[7];
  const float* b1o = (const float*)d_in[8];
  const float* w2u = (const float*)d_in[9];
  const float* b2u = (const float*)d_in[10];
  const float* w2o = (const float*)d_in[13];
  const float* b2o = (const float*)d_in[14];
  const float* w3u = (const float*)d_in[15];
  const float* b3u = (const float*)d_in[16];
  const float* w3o = (const float*)d_in[19];
  const float* b3o = (const float*)d_in[20];

  float* out = (float*)d_out;                    // [B][9]
  float* x1 = out + (size_t)BATCH * 9;           // [B][288]
  float* x2 = x1 + (size_t)BATCH * 288;          // [B][576]
  float* x3 = x2 + (size_t)BATCH * 576;          // [B][144]

  unsigned short* BT2 = (unsigned short*)d_ws;   // [2][576][288] bf16
  unsigned short* BT3 = BT2 + 331776;            // [2][144][576] bf16
  float* A1 = (float*)((char*)d_ws + 995328);    // [2][9][288] fp32

  build_bt<<<1296, 256, 0, stream>>>(w2u, w2o, BT2, 64, 32, 96);
  build_bt<<<648, 256, 0, stream>>>(w3u, w3o, BT3, 16, 64, 80);
  build_a1<<<21, 256, 0, stream>>>(w1u, w1o, A1);

  megafused<<<BATCH / 64, 256, 0, stream>>>(inputs, A1, b1u, b1o, BT2, b2u, b2o,
                                            BT3, b3u, b3o, wd, bd, x1, x2, x3, out);
}

// Round 6
// 163.713 us; speedup vs baseline: 1.7104x; 1.1345x over previous
//
#include <hip/hip_runtime.h>

#define BATCH 65536

typedef __attribute__((ext_vector_type(8))) short bf16x8;
typedef __attribute__((ext_vector_type(4))) float f32x4;

__device__ __forceinline__ unsigned short f2bf(float f) {
  unsigned int u = __float_as_uint(f);
  u += 0x7fffu + ((u >> 16) & 1u);   // RNE (used in one-time weight builds only)
  return (unsigned short)(u >> 16);
}
// trunc-pack 2 floats -> 1 dword of 2 bf16 (lo in low half), single v_perm_b32
__device__ __forceinline__ unsigned pack_trunc(float lo, float hi) {
  return __builtin_amdgcn_perm(__float_as_uint(hi), __float_as_uint(lo), 0x07060302u);
}

// tanh(o)*sigmoid(u): 2 exp + 1 rcp. Lower-bound clamps keep exp finite ->
// no NaN possible even on garbage inputs (inf denom -> rcp=0 -> finite*0=0).
__device__ __forceinline__ float gru_act(float u, float o) {
  u = fmaxf(u, -60.0f);
  o = fmaxf(o, -30.0f);
  float a  = __expf(-u);
  float a2 = __expf(-2.0f * o);
  return (1.0f - a2) * __builtin_amdgcn_rcpf((1.0f + a) * (1.0f + a2));
}

// conv 3x3 SAME on 3x3 grid, unrolled tap value
__device__ __forceinline__ float conv_tap(const float* __restrict__ w, int co, int ci,
                                          int p, int q, int CINTOT) {
  int pi = p / 3, pj = p % 3, qi = q / 3, qj = q % 3;
  int di = qi - pi + 1, dj = qj - pj + 1;
  if ((unsigned)di < 3u && (unsigned)dj < 3u)
    return w[((co * CINTOT + ci) * 3 + di) * 3 + dj];
  return 0.0f;
}

// BT[g][n][k] bf16, n = co*9+p, k = ci*9+q
__global__ void build_bt(const float* __restrict__ wu, const float* __restrict__ wo,
                         unsigned short* __restrict__ BT, int COUT, int CINX, int CINTOT) {
  int NG = COUT * 9, K = CINX * 9;
  int total = 2 * NG * K;
  int e = blockIdx.x * 256 + threadIdx.x;
  if (e >= total) return;
  int g = e / (NG * K);
  int rem = e - g * (NG * K);
  int n = rem / K, k = rem - n * K;
  BT[e] = f2bf(conv_tap(g ? wo : wu, n / 9, k / 9, n % 9, k % 9, CINTOT));
}

// A1 transposed: [g][q][c], c = col n in [0,288), q = input tap in [0,9)
__global__ void build_a1(const float* __restrict__ wu, const float* __restrict__ wo,
                         float* __restrict__ A1) {
  int e = blockIdx.x * 256 + threadIdx.x;
  if (e >= 5184) return;
  int g = e / 2592;
  int rem = e - g * 2592;
  int q = rem / 288, c = rem - q * 288;
  A1[e] = conv_tap(g ? wo : wu, c / 9, 0, c % 9, q, 33);
}

// ---------------- LDS layout (bytes), lifetimes barrier-separated ----------------
#define OFF_X1L 0
#define OFF_X3L 0
#define OFF_WL 20480
#define OFF_BLB 25664
#define OFF_BL 40960
#define OFF_XL 65536
#define OFF_AL 65536
#define SMEM_BYTES 69632

__global__ __launch_bounds__(256, 2) void megafused(
    const float* __restrict__ xin, const float* __restrict__ A1,
    const float* __restrict__ b1u, const float* __restrict__ b1o,
    const unsigned short* __restrict__ BT2,
    const float* __restrict__ b2u, const float* __restrict__ b2o,
    const unsigned short* __restrict__ BT3,
    const float* __restrict__ b3u, const float* __restrict__ b3o,
    const float* __restrict__ wd, const float* __restrict__ bd,
    float* __restrict__ x1, float* __restrict__ x2,
    float* __restrict__ x3, float* __restrict__ out) {
  __shared__ __align__(16) char smem[SMEM_BYTES];
  char* x1l = smem + OFF_X1L;
  char* Bl = smem + OFF_BL;
  char* Al = smem + OFF_AL;
  unsigned short* x3l = (unsigned short*)(smem + OFF_X3L);
  float* xl = (float*)(smem + OFF_XL);
  float* wl = (float*)(smem + OFF_WL);
  float* blb = (float*)(smem + OFF_BLB);

  const int tid = threadIdx.x;
  const int lane = tid & 63;
  const int wid = tid >> 6;
  const int lrow = lane & 15;
  const int jc = lane >> 4;
  const int r0 = blockIdx.x * 64;
  const int srow = tid >> 2, spart = tid & 3;   // staging coords

  // L2 B-staging: thread-constant offsets/addresses
  unsigned toffB2[6];
  char* wB2[6];
#pragma unroll
  for (int ci = 0; ci < 6; ++ci) {
    int row = ci * 64 + srow;                 // 0..383
    int bg = (row < 192) ? row : (384 + row); // gate base row in BT2
    toffB2[ci] = (unsigned)bg * 288u + spart * 8;
    wB2[ci] = Bl + row * 64 + ((spart ^ ((row >> 1) & 3)) << 4);
  }

  // stage x input
  for (int c = tid; c < 576; c += 256) xl[(c / 9) * 12 + (c % 9)] = xin[(size_t)r0 * 9 + c];
  __syncthreads();

  // issue L2 step-0 B loads NOW: in flight across all of L1 (no barrier until
  // step-0's barrier, and the LDS-write consumes them via register dependency)
  bf16x8 pf[6];
#pragma unroll
  for (int ci = 0; ci < 6; ++ci) pf[ci] = *(const bf16x8*)(BT2 + toffB2[ci]);

  // ---- L1: exact fp32, lanes = cols ----
  {
    float au0[9], ao0[9], au1[9], ao1[9];
    const int c1 = tid, c2 = tid + 256;
    const bool has2 = (c2 < 288);
#pragma unroll
    for (int q = 0; q < 9; ++q) {
      au0[q] = A1[q * 288 + c1];
      ao0[q] = A1[2592 + q * 288 + c1];
      au1[q] = has2 ? A1[q * 288 + c2] : 0.0f;
      ao1[q] = has2 ? A1[2592 + q * 288 + c2] : 0.0f;
    }
    float bu0 = b1u[c1 / 9], bo0 = b1o[c1 / 9];
    float bu1 = has2 ? b1u[c2 / 9] : 0.0f;
    float bo1 = has2 ? b1o[c2 / 9] : 0.0f;
    for (int r = 0; r < 64; ++r) {
      const float4 xv0 = *(const float4*)&xl[r * 12];
      const float4 xv1 = *(const float4*)&xl[r * 12 + 4];
      const float x8 = xl[r * 12 + 8];
      float u0 = bu0, o0 = bo0, u1 = bu1, o1 = bo1;
      u0 = fmaf(au0[0], xv0.x, u0); o0 = fmaf(ao0[0], xv0.x, o0);
      u0 = fmaf(au0[1], xv0.y, u0); o0 = fmaf(ao0[1], xv0.y, o0);
      u0 = fmaf(au0[2], xv0.z, u0); o0 = fmaf(ao0[2], xv0.z, o0);
      u0 = fmaf(au0[3], xv0.w, u0); o0 = fmaf(ao0[3], xv0.w, o0);
      u0 = fmaf(au0[4], xv1.x, u0); o0 = fmaf(ao0[4], xv1.x, o0);
      u0 = fmaf(au0[5], xv1.y, u0); o0 = fmaf(ao0[5], xv1.y, o0);
      u0 = fmaf(au0[6], xv1.z, u0); o0 = fmaf(ao0[6], xv1.z, o0);
      u0 = fmaf(au0[7], xv1.w, u0); o0 = fmaf(ao0[7], xv1.w, o0);
      u0 = fmaf(au0[8], x8, u0);    o0 = fmaf(ao0[8], x8, o0);
      float v0 = gru_act(u0, o0);
      x1[(size_t)(r0 + r) * 288 + c1] = v0;
      *(unsigned short*)(x1l + r * 640 + (((c1 >> 3) ^ (r & 7)) << 4) + (c1 & 7) * 2) =
          (unsigned short)(__float_as_uint(v0) >> 16);
      if (has2) {
        u1 = fmaf(au1[0], xv0.x, u1); o1 = fmaf(ao1[0], xv0.x, o1);
        u1 = fmaf(au1[1], xv0.y, u1); o1 = fmaf(ao1[1], xv0.y, o1);
        u1 = fmaf(au1[2], xv0.z, u1); o1 = fmaf(ao1[2], xv0.z, o1);
        u1 = fmaf(au1[3], xv0.w, u1); o1 = fmaf(ao1[3], xv0.w, o1);
        u1 = fmaf(au1[4], xv1.x, u1); o1 = fmaf(ao1[4], xv1.x, o1);
        u1 = fmaf(au1[5], xv1.y, u1); o1 = fmaf(ao1[5], xv1.y, o1);
        u1 = fmaf(au1[6], xv1.z, u1); o1 = fmaf(ao1[6], xv1.z, o1);
        u1 = fmaf(au1[7], xv1.w, u1); o1 = fmaf(ao1[7], xv1.w, o1);
        u1 = fmaf(au1[8], x8, u1);    o1 = fmaf(ao1[8], x8, o1);
        float v1 = gru_act(u1, o1);
        x1[(size_t)(r0 + r) * 288 + c2] = v1;
        *(unsigned short*)(x1l + r * 640 + (((c2 >> 3) ^ (r & 7)) << 4) + (c2 & 7) * 2) =
            (unsigned short)(__float_as_uint(v1) >> 16);
      }
    }
  }

  // ---- L2: x1l(bf16) x BT2 -> x2 global fp32. 27 steps, prefetch issued
  //      AFTER barrier1 so barrier2's vmcnt(0) drain is covered by frags+MFMA ----
  {
    const char* rB[2][3];
#pragma unroll
    for (int g = 0; g < 2; ++g)
#pragma unroll
      for (int f = 0; f < 3; ++f) {
        int rb = g * 192 + (wid * 3 + f) * 16 + lrow;
        rB[g][f] = Bl + rb * 64 + ((jc ^ ((rb >> 1) & 3)) << 4);
      }
    const char* aBase[4];
    int aXor[4];
#pragma unroll
    for (int m = 0; m < 4; ++m) {
      int row = m * 16 + lrow;
      aBase[m] = x1l + row * 640;
      aXor[m] = row & 7;
    }

    f32x4 acc[4][2][3] = {};
    for (int s = 0; s < 27; ++s) {
      const int kt = s - (s / 9) * 9;
      // write staged B to LDS (register dependency waits on pf loads)
#pragma unroll
      for (int ci = 0; ci < 6; ++ci) *(bf16x8*)wB2[ci] = pf[ci];
      __syncthreads();   // Bl ready; (s=0) x1l writes visible
      // issue next-step loads (drained at barrier2, under frags+MFMA cover)
      if (s < 26) {
        int ns = s + 1;
        unsigned uoff = (unsigned)(ns / 9) * 55296u + (unsigned)(ns % 9) * 32u;
#pragma unroll
        for (int ci = 0; ci < 6; ++ci)
          pf[ci] = *(const bf16x8*)(BT2 + uoff + toffB2[ci]);
      }
      bf16x8 af[4];
      const int c8 = kt * 4 + jc;
#pragma unroll
      for (int m = 0; m < 4; ++m)
        af[m] = *(const bf16x8*)(aBase[m] + ((c8 ^ aXor[m]) << 4));
      bf16x8 bfr[2][3];
#pragma unroll
      for (int g = 0; g < 2; ++g)
#pragma unroll
        for (int f = 0; f < 3; ++f) bfr[g][f] = *(const bf16x8*)rB[g][f];
#pragma unroll
      for (int m = 0; m < 4; ++m)
#pragma unroll
        for (int g = 0; g < 2; ++g)
#pragma unroll
          for (int f = 0; f < 3; ++f)
            acc[m][g][f] = __builtin_amdgcn_mfma_f32_16x16x32_bf16(
                af[m], bfr[g][f], acc[m][g][f], 0, 0, 0);
      if (kt == 8) {
        const int n0 = (s / 9) * 192;
#pragma unroll
        for (int m = 0; m < 4; ++m)
#pragma unroll
          for (int f = 0; f < 3; ++f) {
            int n = n0 + (wid * 3 + f) * 16 + lrow;
            float bU = b2u[n / 9], bO = b2o[n / 9];
            f32x4 u = acc[m][0][f], o = acc[m][1][f];
#pragma unroll
            for (int t = 0; t < 4; ++t) {
              int r = r0 + m * 16 + jc * 4 + t;
              x2[(size_t)r * 576 + n] = gru_act(u[t] + bU, o[t] + bO);
            }
            acc[m][0][f] = (f32x4){0.f, 0.f, 0.f, 0.f};
            acc[m][1][f] = (f32x4){0.f, 0.f, 0.f, 0.f};
          }
      }
      __syncthreads();   // Bl consumers done; drains prefetch (covered)
    }
  }
  // (final step's barrier2 already separates x1l/Bl lifetimes)

  // ---- L3: x2 (L2-hot readback) x BT3, same prefetch discipline ----
  {
    unsigned toffB3[5];
    char* wB3[5];
#pragma unroll
    for (int j = 0; j < 5; ++j) {
      int c = j * 256 + tid;
      if (c < 1152) {
        int row = c >> 2, part = c & 3;
        toffB3[j] = (unsigned)row * 576u + part * 8;
        wB3[j] = Bl + row * 64 + ((part ^ ((row >> 1) & 3)) << 4);
      } else {
        toffB3[j] = 0; wB3[j] = Bl;  // unused
      }
    }
    const float* pA = x2 + (size_t)(r0 + srow) * 576 + spart * 8;
    char* wAl = Al + srow * 64 + ((spart ^ ((srow >> 1) & 3)) << 4);

    // issue kt=0 loads (covered by wl staging)
    float4 pa0 = *(const float4*)pA;
    float4 pa1 = *(const float4*)(pA + 4);
    bf16x8 pb[5];
#pragma unroll
    for (int j = 0; j < 5; ++j)
      if (j * 256 + tid < 1152) pb[j] = *(const bf16x8*)(BT3 + toffB3[j]);

    // stage dense weights (region disjoint from x3l; visible by L3 barrier1)
    for (int c = tid; c < 1296; c += 256) wl[c] = wd[c];
    if (tid < 9) blb[tid] = bd[tid];

    // fully thread-constant frag addresses
    const char* rB3[2][3];
#pragma unroll
    for (int g = 0; g < 2; ++g)
#pragma unroll
      for (int f = 0; f < 3; ++f) {
        int rb = g * 144 + (wid * 3 + f) * 16 + lrow;
        rB3[g][f] = Bl + rb * 64 + ((jc ^ ((rb >> 1) & 3)) << 4);
      }
    const char* rA3[4];
#pragma unroll
    for (int m = 0; m < 4; ++m) {
      int row = m * 16 + lrow;
      rA3[m] = Al + row * 64 + ((jc ^ ((row >> 1) & 3)) << 4);
    }

    f32x4 acc[4][2][3] = {};
    for (int kt = 0; kt < 18; ++kt) {
      // A: trunc-pack + write
      uint4 h;
      h.x = pack_trunc(pa0.x, pa0.y);
      h.y = pack_trunc(pa0.z, pa0.w);
      h.z = pack_trunc(pa1.x, pa1.y);
      h.w = pack_trunc(pa1.z, pa1.w);
      *(uint4*)wAl = h;
#pragma unroll
      for (int j = 0; j < 5; ++j)
        if (j * 256 + tid < 1152) *(bf16x8*)wB3[j] = pb[j];
      __syncthreads();   // Al/Bl ready
      if (kt < 17) {
        const float* gp = pA + (kt + 1) * 32;
        pa0 = *(const float4*)gp;
        pa1 = *(const float4*)(gp + 4);
        unsigned uoff = (unsigned)(kt + 1) * 32u;
#pragma unroll
        for (int j = 0; j < 5; ++j)
          if (j * 256 + tid < 1152) pb[j] = *(const bf16x8*)(BT3 + uoff + toffB3[j]);
      }
      if (wid < 3) {
        bf16x8 af[4];
#pragma unroll
        for (int m = 0; m < 4; ++m) af[m] = *(const bf16x8*)rA3[m];
        bf16x8 bfr[2][3];
#pragma unroll
        for (int g = 0; g < 2; ++g)
#pragma unroll
          for (int f = 0; f < 3; ++f) bfr[g][f] = *(const bf16x8*)rB3[g][f];
#pragma unroll
        for (int m = 0; m < 4; ++m)
#pragma unroll
          for (int g = 0; g < 2; ++g)
#pragma unroll
            for (int f = 0; f < 3; ++f)
              acc[m][g][f] = __builtin_amdgcn_mfma_f32_16x16x32_bf16(
                  af[m], bfr[g][f], acc[m][g][f], 0, 0, 0);
      }
      __syncthreads();
    }
    // epilogue: act -> x3 global fp32 + x3l (LDS bf16, trunc)
    if (wid < 3) {
#pragma unroll
      for (int m = 0; m < 4; ++m)
#pragma unroll
        for (int f = 0; f < 3; ++f) {
          int n = (wid * 3 + f) * 16 + lrow;
          float bU = b3u[n / 9], bO = b3o[n / 9];
          f32x4 u = acc[m][0][f], o = acc[m][1][f];
#pragma unroll
          for (int t = 0; t < 4; ++t) {
            int r = m * 16 + jc * 4 + t;
            float v = gru_act(u[t] + bU, o[t] + bO);
            x3[(size_t)(r0 + r) * 144 + n] = v;
            x3l[r * 146 + n] = (unsigned short)(__float_as_uint(v) >> 16);
          }
        }
    }
  }
  __syncthreads();   // x3l ready

  // ---- dense head: 3 waves, 3 cols each ----
  if (wid < 3) {
    int drow = lane;
    int jb = wid * 3;
    float s0 = blb[jb], s1 = blb[jb + 1], s2 = blb[jb + 2];
    for (int k = 0; k < 144; k += 2) {
      unsigned pr = *(const unsigned*)&x3l[drow * 146 + k];
      float v0 = __uint_as_float(pr << 16);
      float v1 = __uint_as_float(pr & 0xffff0000u);
      const float2 w0 = *(const float2*)&wl[jb * 144 + k];
      const float2 w1 = *(const float2*)&wl[(jb + 1) * 144 + k];
      const float2 w2 = *(const float2*)&wl[(jb + 2) * 144 + k];
      s0 = fmaf(v0, w0.x, s0); s0 = fmaf(v1, w0.y, s0);
      s1 = fmaf(v0, w1.x, s1); s1 = fmaf(v1, w1.y, s1);
      s2 = fmaf(v0, w2.x, s2); s2 = fmaf(v1, w2.y, s2);
    }
    size_t ob = (size_t)(r0 + drow) * 9 + jb;
    out[ob] = s0; out[ob + 1] = s1; out[ob + 2] = s2;
  }
}

extern "C" void kernel_launch(void* const* d_in, const int* in_sizes, int n_in,
                              void* d_out, int out_size, void* d_ws, size_t ws_size,
                              hipStream_t stream) {
  const float* inputs = (const float*)d_in[0];
  const float* wd  = (const float*)d_in[1];
  const float* bd  = (const float*)d_in[2];
  const float* w1u = (const float*)d_in[3];
  const float* b1u = (const float*)d_in[4];
  const float* w1o = (const float*)d_in[7];
  const float* b1o = (const float*)d_in[8];
  const float* w2u = (const float*)d_in[9];
  const float* b2u = (const float*)d_in[10];
  const float* w2o = (const float*)d_in[13];
  const float* b2o = (const float*)d_in[14];
  const float* w3u = (const float*)d_in[15];
  const float* b3u = (const float*)d_in[16];
  const float* w3o = (const float*)d_in[19];
  const float* b3o = (const float*)d_in[20];

  float* out = (float*)d_out;                    // [B][9]
  float* x1 = out + (size_t)BATCH * 9;           // [B][288]
  float* x2 = x1 + (size_t)BATCH * 288;          // [B][576]
  float* x3 = x2 + (size_t)BATCH * 576;          // [B][144]

  unsigned short* BT2 = (unsigned short*)d_ws;   // [2][576][288] bf16
  unsigned short* BT3 = BT2 + 331776;            // [2][144][576] bf16
  float* A1 = (float*)((char*)d_ws + 995328);    // [2][9][288] fp32

  build_bt<<<1296, 256, 0, stream>>>(w2u, w2o, BT2, 64, 32, 96);
  build_bt<<<648, 256, 0, stream>>>(w3u, w3o, BT3, 16, 64, 80);
  build_a1<<<21, 256, 0, stream>>>(w1u, w1o, A1);

  megafused<<<BATCH / 64, 256, 0, stream>>>(inputs, A1, b1u, b1o, BT2, b2u, b2o,
                                            BT3, b3u, b3o, wd, bd, x1, x2, x3, out);
}

// Round 7
// 163.521 us; speedup vs baseline: 1.7124x; 1.0012x over previous
//
#include <hip/hip_runtime.h>

#define BATCH 65536

typedef __attribute__((ext_vector_type(8))) short bf16x8;
typedef __attribute__((ext_vector_type(4))) float f32x4;

__device__ __forceinline__ unsigned short f2bf(float f) {
  unsigned int u = __float_as_uint(f);
  u += 0x7fffu + ((u >> 16) & 1u);   // RNE (one-time weight builds only)
  return (unsigned short)(u >> 16);
}
// trunc-pack 2 floats -> 1 dword of 2 bf16 (lo in low half), single v_perm_b32
__device__ __forceinline__ unsigned pack_trunc(float lo, float hi) {
  return __builtin_amdgcn_perm(__float_as_uint(hi), __float_as_uint(lo), 0x07060302u);
}

// tanh(o)*sigmoid(u): 2 exp + 1 rcp; lower-bound clamps keep it NaN-proof.
__device__ __forceinline__ float gru_act(float u, float o) {
  u = fmaxf(u, -60.0f);
  o = fmaxf(o, -30.0f);
  float a  = __expf(-u);
  float a2 = __expf(-2.0f * o);
  return (1.0f - a2) * __builtin_amdgcn_rcpf((1.0f + a) * (1.0f + a2));
}

// conv 3x3 SAME on 3x3 grid, unrolled tap value
__device__ __forceinline__ float conv_tap(const float* __restrict__ w, int co, int ci,
                                          int p, int q, int CINTOT) {
  int pi = p / 3, pj = p % 3, qi = q / 3, qj = q % 3;
  int di = qi - pi + 1, dj = qj - pj + 1;
  if ((unsigned)di < 3u && (unsigned)dj < 3u)
    return w[((co * CINTOT + ci) * 3 + di) * 3 + dj];
  return 0.0f;
}

// BT[g][n][k] bf16, n = co*9+p, k = ci*9+q
__global__ void build_bt(const float* __restrict__ wu, const float* __restrict__ wo,
                         unsigned short* __restrict__ BT, int COUT, int CINX, int CINTOT) {
  int NG = COUT * 9, K = CINX * 9;
  int total = 2 * NG * K;
  int e = blockIdx.x * 256 + threadIdx.x;
  if (e >= total) return;
  int g = e / (NG * K);
  int rem = e - g * (NG * K);
  int n = rem / K, k = rem - n * K;
  BT[e] = f2bf(conv_tap(g ? wo : wu, n / 9, k / 9, n % 9, k % 9, CINTOT));
}

// A1 transposed: [g][q][c], c = col n in [0,288), q = input tap in [0,9)
__global__ void build_a1(const float* __restrict__ wu, const float* __restrict__ wo,
                         float* __restrict__ A1) {
  int e = blockIdx.x * 256 + threadIdx.x;
  if (e >= 5184) return;
  int g = e / 2592;
  int rem = e - g * 2592;
  int q = rem / 288, c = rem - q * 288;
  A1[e] = conv_tap(g ? wo : wu, c / 9, 0, c % 9, q, 33);
}

// ---------------- LDS layout (bytes), lifetimes barrier-separated ----------------
// [0,40960)  x1l (L1..L2)  | x3l [0,18688) (L3 epi..dense) | wl [20480,25664)+blb (post-L2)
// [40960,65536) Bl 384x64
// [65536,69632) Al 64x64 (L3) | xl 64x12 f32 (L1)
#define OFF_X1L 0
#define OFF_X3L 0
#define OFF_WL 20480
#define OFF_BLB 25664
#define OFF_BL 40960
#define OFF_XL 65536
#define OFF_AL 65536
#define SMEM_BYTES 69632

__global__ __launch_bounds__(512, 4) void megafused(
    const float* __restrict__ xin, const float* __restrict__ A1,
    const float* __restrict__ b1u, const float* __restrict__ b1o,
    const unsigned short* __restrict__ BT2,
    const float* __restrict__ b2u, const float* __restrict__ b2o,
    const unsigned short* __restrict__ BT3,
    const float* __restrict__ b3u, const float* __restrict__ b3o,
    const float* __restrict__ wd, const float* __restrict__ bd,
    float* __restrict__ x1, float* __restrict__ x2,
    float* __restrict__ x3, float* __restrict__ out) {
  __shared__ __align__(16) char smem[SMEM_BYTES];
  char* x1l = smem + OFF_X1L;
  char* Bl = smem + OFF_BL;
  char* Al = smem + OFF_AL;
  unsigned short* x3l = (unsigned short*)(smem + OFF_X3L);
  float* xl = (float*)(smem + OFF_XL);
  float* wl = (float*)(smem + OFF_WL);
  float* blb = (float*)(smem + OFF_BLB);

  const int tid = threadIdx.x;
  const int lane = tid & 63;
  const int wid = tid >> 6;          // 0..7
  const int lrow = lane & 15;
  const int jc = (lane >> 4) & 3;
  const int mh = wid >> 2;           // row half
  const int cg = wid & 3;            // col group
  const int r0 = blockIdx.x * 64;
  const int srow = tid >> 2, spart = tid & 3;   // staging coords (1536 chunks / 512)

  // L2 B-staging thread-constants: 3 chunks/thread, rows ci*128+srow in [0,384)
  unsigned toffB2[3];
  char* wB2[3];
#pragma unroll
  for (int ci = 0; ci < 3; ++ci) {
    int row = ci * 128 + srow;
    int bg = (row < 192) ? row : (384 + row);   // BT2 row (gate1 at 576)
    toffB2[ci] = (unsigned)bg * 288u + spart * 8;
    wB2[ci] = Bl + row * 64 + ((spart ^ ((row >> 1) & 3)) << 4);
  }

  // stage x input
  for (int c = tid; c < 576; c += 512) xl[(c / 9) * 12 + (c % 9)] = xin[(size_t)r0 * 9 + c];
  __syncthreads();

  // issue L2 step-0 B loads (in flight across all of L1)
  bf16x8 pf[3];
#pragma unroll
  for (int ci = 0; ci < 3; ++ci) pf[ci] = *(const bf16x8*)(BT2 + toffB2[ci]);

  // ---- L1: exact fp32. 1152 units = 288 cols x 4 row-quarters ----
  for (int uu = 0; uu < 3; ++uu) {
    int u = tid + (uu << 9);
    if (u < 1152) {
      int c = u >> 2, rq = u & 3;
      float au[9], ao[9];
#pragma unroll
      for (int q = 0; q < 9; ++q) {
        au[q] = A1[q * 288 + c];
        ao[q] = A1[2592 + q * 288 + c];
      }
      float bU = b1u[c / 9], bO = b1o[c / 9];
      const int cbase = c >> 3, cb = (c & 7) * 2;
#pragma unroll 4
      for (int i = 0; i < 16; ++i) {
        int r = (rq << 4) + i;
        const float4 xv0 = *(const float4*)&xl[r * 12];
        const float4 xv1 = *(const float4*)&xl[r * 12 + 4];
        const float x8 = xl[r * 12 + 8];
        float uacc = bU, oacc = bO;
        uacc = fmaf(au[0], xv0.x, uacc); oacc = fmaf(ao[0], xv0.x, oacc);
        uacc = fmaf(au[1], xv0.y, uacc); oacc = fmaf(ao[1], xv0.y, oacc);
        uacc = fmaf(au[2], xv0.z, uacc); oacc = fmaf(ao[2], xv0.z, oacc);
        uacc = fmaf(au[3], xv0.w, uacc); oacc = fmaf(ao[3], xv0.w, oacc);
        uacc = fmaf(au[4], xv1.x, uacc); oacc = fmaf(ao[4], xv1.x, oacc);
        uacc = fmaf(au[5], xv1.y, uacc); oacc = fmaf(ao[5], xv1.y, oacc);
        uacc = fmaf(au[6], xv1.z, uacc); oacc = fmaf(ao[6], xv1.z, oacc);
        uacc = fmaf(au[7], xv1.w, uacc); oacc = fmaf(ao[7], xv1.w, oacc);
        uacc = fmaf(au[8], x8, uacc);    oacc = fmaf(ao[8], x8, oacc);
        float v = gru_act(uacc, oacc);
        x1[(size_t)(r0 + r) * 288 + c] = v;
        *(unsigned short*)(x1l + r * 640 + ((cbase ^ (r & 7)) << 4) + cb) =
            (unsigned short)(__float_as_uint(v) >> 16);
      }
    }
  }

  // ---- L2: x1l(bf16) x BT2 -> x2 global fp32. 27 steps, depth-1 prefetch ----
  {
    const char* rB[2][3];
#pragma unroll
    for (int g = 0; g < 2; ++g)
#pragma unroll
      for (int f = 0; f < 3; ++f) {
        int rb = g * 192 + (cg * 3 + f) * 16 + lrow;
        rB[g][f] = Bl + rb * 64 + ((jc ^ ((rb >> 1) & 3)) << 4);
      }
    const char* aBase[2];
    int aXor[2];
#pragma unroll
    for (int m = 0; m < 2; ++m) {
      int row = mh * 32 + m * 16 + lrow;
      aBase[m] = x1l + row * 640;
      aXor[m] = row & 7;
    }

    f32x4 acc[2][2][3] = {};
    for (int s = 0; s < 27; ++s) {
      const int kt = s - (s / 9) * 9;
#pragma unroll
      for (int ci = 0; ci < 3; ++ci) *(bf16x8*)wB2[ci] = pf[ci];
      __syncthreads();   // Bl ready; (s=0) x1l writes visible
      if (s < 26) {
        int ns = s + 1;
        unsigned uoff = (unsigned)(ns / 9) * 55296u + (unsigned)(ns % 9) * 32u;
#pragma unroll
        for (int ci = 0; ci < 3; ++ci)
          pf[ci] = *(const bf16x8*)(BT2 + uoff + toffB2[ci]);
      }
      bf16x8 af[2];
      const int c8 = kt * 4 + jc;
#pragma unroll
      for (int m = 0; m < 2; ++m)
        af[m] = *(const bf16x8*)(aBase[m] + ((c8 ^ aXor[m]) << 4));
      bf16x8 bfr[2][3];
#pragma unroll
      for (int g = 0; g < 2; ++g)
#pragma unroll
        for (int f = 0; f < 3; ++f) bfr[g][f] = *(const bf16x8*)rB[g][f];
#pragma unroll
      for (int m = 0; m < 2; ++m)
#pragma unroll
        for (int g = 0; g < 2; ++g)
#pragma unroll
          for (int f = 0; f < 3; ++f)
            acc[m][g][f] = __builtin_amdgcn_mfma_f32_16x16x32_bf16(
                af[m], bfr[g][f], acc[m][g][f], 0, 0, 0);
      if (kt == 8) {
        const int n0 = (s / 9) * 192;
#pragma unroll
        for (int m = 0; m < 2; ++m)
#pragma unroll
          for (int f = 0; f < 3; ++f) {
            int n = n0 + (cg * 3 + f) * 16 + lrow;
            float bU = b2u[n / 9], bO = b2o[n / 9];
            f32x4 u = acc[m][0][f], o = acc[m][1][f];
#pragma unroll
            for (int t = 0; t < 4; ++t) {
              int r = r0 + mh * 32 + m * 16 + jc * 4 + t;
              x2[(size_t)r * 576 + n] = gru_act(u[t] + bU, o[t] + bO);
            }
            acc[m][0][f] = (f32x4){0.f, 0.f, 0.f, 0.f};
            acc[m][1][f] = (f32x4){0.f, 0.f, 0.f, 0.f};
          }
      }
      __syncthreads();   // Bl consumers done; drains prefetch (covered)
    }
  }

  // ---- L3: x2 (L2-hot readback) x BT3 (N padded 144->192), same discipline ----
  {
    // B staging: 1536 chunks over 384 rows (2 gates x 192, zero-pad nloc>=144)
    unsigned toffB3[3];
    char* wB3[3];
    bool vB3[3];
#pragma unroll
    for (int ci = 0; ci < 3; ++ci) {
      int row = ci * 128 + srow;
      int g = row >= 192;
      int nloc = row - (g ? 192 : 0);
      vB3[ci] = (nloc < 144);
      toffB3[ci] = (unsigned)((g ? 144 : 0) + nloc) * 576u + spart * 8;
      wB3[ci] = Bl + row * 64 + ((spart ^ ((row >> 1) & 3)) << 4);
    }
    // A staging: tid<256 handles row = tid>>2 in [0,64)
    const float* pA = x2 + (size_t)(r0 + (tid >> 2)) * 576 + spart * 8;
    char* wAl = Al + (tid >> 2) * 64 + ((spart ^ (((tid >> 2) >> 1) & 3)) << 4);

    // issue kt=0 loads (covered by wl staging below)
    float4 pa0 = {}, pa1 = {};
    if (tid < 256) {
      pa0 = *(const float4*)pA;
      pa1 = *(const float4*)(pA + 4);
    }
    bf16x8 pb[3];
#pragma unroll
    for (int ci = 0; ci < 3; ++ci)
      pb[ci] = vB3[ci] ? *(const bf16x8*)(BT3 + toffB3[ci])
                       : (bf16x8){0, 0, 0, 0, 0, 0, 0, 0};

    // stage dense weights (regions disjoint from x3l; visible by L3 barrier1)
    for (int c = tid; c < 1296; c += 512) wl[c] = wd[c];
    if (tid < 9) blb[tid] = bd[tid];

    const char* rB3[2][3];
#pragma unroll
    for (int g = 0; g < 2; ++g)
#pragma unroll
      for (int f = 0; f < 3; ++f) {
        int rb = g * 192 + (cg * 3 + f) * 16 + lrow;
        rB3[g][f] = Bl + rb * 64 + ((jc ^ ((rb >> 1) & 3)) << 4);
      }
    const char* rA3[2];
#pragma unroll
    for (int m = 0; m < 2; ++m) {
      int row = mh * 32 + m * 16 + lrow;
      rA3[m] = Al + row * 64 + ((jc ^ ((row >> 1) & 3)) << 4);
    }

    f32x4 acc[2][2][3] = {};
    for (int kt = 0; kt < 18; ++kt) {
      if (tid < 256) {
        uint4 h;
        h.x = pack_trunc(pa0.x, pa0.y);
        h.y = pack_trunc(pa0.z, pa0.w);
        h.z = pack_trunc(pa1.x, pa1.y);
        h.w = pack_trunc(pa1.z, pa1.w);
        *(uint4*)wAl = h;
      }
#pragma unroll
      for (int ci = 0; ci < 3; ++ci) *(bf16x8*)wB3[ci] = pb[ci];
      __syncthreads();   // Al/Bl ready; wl/blb visible (kt=0)
      if (kt < 17) {
        if (tid < 256) {
          const float* gp = pA + (kt + 1) * 32;
          pa0 = *(const float4*)gp;
          pa1 = *(const float4*)(gp + 4);
        }
        unsigned uoff = (unsigned)(kt + 1) * 32u;
#pragma unroll
        for (int ci = 0; ci < 3; ++ci)
          if (vB3[ci]) pb[ci] = *(const bf16x8*)(BT3 + uoff + toffB3[ci]);
      }
      bf16x8 af[2];
#pragma unroll
      for (int m = 0; m < 2; ++m) af[m] = *(const bf16x8*)rA3[m];
      bf16x8 bfr[2][3];
#pragma unroll
      for (int g = 0; g < 2; ++g)
#pragma unroll
        for (int f = 0; f < 3; ++f) bfr[g][f] = *(const bf16x8*)rB3[g][f];
#pragma unroll
      for (int m = 0; m < 2; ++m)
#pragma unroll
        for (int g = 0; g < 2; ++g)
#pragma unroll
          for (int f = 0; f < 3; ++f)
            acc[m][g][f] = __builtin_amdgcn_mfma_f32_16x16x32_bf16(
                af[m], bfr[g][f], acc[m][g][f], 0, 0, 0);
      __syncthreads();
    }
    // epilogue: cg<3 carry real cols (n<144): act -> x3 global + x3l (trunc)
    if (cg < 3) {
#pragma unroll
      for (int m = 0; m < 2; ++m)
#pragma unroll
        for (int f = 0; f < 3; ++f) {
          int n = (cg * 3 + f) * 16 + lrow;
          float bU = b3u[n / 9], bO = b3o[n / 9];
          f32x4 u = acc[m][0][f], o = acc[m][1][f];
#pragma unroll
          for (int t = 0; t < 4; ++t) {
            int r = mh * 32 + m * 16 + jc * 4 + t;
            float v = gru_act(u[t] + bU, o[t] + bO);
            x3[(size_t)(r0 + r) * 144 + n] = v;
            x3l[r * 146 + n] = (unsigned short)(__float_as_uint(v) >> 16);
          }
        }
    }
  }
  __syncthreads();   // x3l ready

  // ---- dense head: 9 cols x 64 rows; wave j = col wid, plus wave0 col 8 ----
  {
    int row = lane;
    int j = wid;
    float s = blb[j];
    for (int k = 0; k < 144; k += 2) {
      unsigned pr = *(const unsigned*)&x3l[row * 146 + k];
      float v0 = __uint_as_float(pr << 16);
      float v1 = __uint_as_float(pr & 0xffff0000u);
      const float2 w0 = *(const float2*)&wl[j * 144 + k];
      s = fmaf(v0, w0.x, s);
      s = fmaf(v1, w0.y, s);
    }
    out[(size_t)(r0 + row) * 9 + j] = s;
    if (tid < 64) {
      float s8 = blb[8];
      for (int k = 0; k < 144; k += 2) {
        unsigned pr = *(const unsigned*)&x3l[row * 146 + k];
        float v0 = __uint_as_float(pr << 16);
        float v1 = __uint_as_float(pr & 0xffff0000u);
        const float2 w0 = *(const float2*)&wl[8 * 144 + k];
        s8 = fmaf(v0, w0.x, s8);
        s8 = fmaf(v1, w0.y, s8);
      }
      out[(size_t)(r0 + row) * 9 + 8] = s8;
    }
  }
}

extern "C" void kernel_launch(void* const* d_in, const int* in_sizes, int n_in,
                              void* d_out, int out_size, void* d_ws, size_t ws_size,
                              hipStream_t stream) {
  const float* inputs = (const float*)d_in[0];
  const float* wd  = (const float*)d_in[1];
  const float* bd  = (const float*)d_in[2];
  const float* w1u = (const float*)d_in[3];
  const float* b1u = (const float*)d_in[4];
  const float* w1o = (const float*)d_in[7];
  const float* b1o = (const float*)d_in[8];
  const float* w2u = (const float*)d_in[9];
  const float* b2u = (const float*)d_in[10];
  const float* w2o = (const float*)d_in[13];
  const float* b2o = (const float*)d_in[14];
  const float* w3u = (const float*)d_in[15];
  const float* b3u = (const float*)d_in[16];
  const float* w3o = (const float*)d_in[19];
  const float* b3o = (const float*)d_in[20];

  float* out = (float*)d_out;                    // [B][9]
  float* x1 = out + (size_t)BATCH * 9;           // [B][288]
  float* x2 = x1 + (size_t)BATCH * 288;          // [B][576]
  float* x3 = x2 + (size_t)BATCH * 576;          // [B][144]

  unsigned short* BT2 = (unsigned short*)d_ws;   // [2][576][288] bf16
  unsigned short* BT3 = BT2 + 331776;            // [2][144][576] bf16
  float* A1 = (float*)((char*)d_ws + 995328);    // [2][9][288] fp32

  build_bt<<<1296, 256, 0, stream>>>(w2u, w2o, BT2, 64, 32, 96);
  build_bt<<<648, 256, 0, stream>>>(w3u, w3o, BT3, 16, 64, 80);
  build_a1<<<21, 256, 0, stream>>>(w1u, w1o, A1);

  megafused<<<BATCH / 64, 512, 0, stream>>>(inputs, A1, b1u, b1o, BT2, b2u, b2o,
                                            BT3, b3u, b3o, wd, bd, x1, x2, x3, out);
}